// Round 1
// baseline (5785.345 us; speedup 1.0000x reference)
//
#include <hip/hip_runtime.h>

#define ND 100000
#define DD 128
#define HH 256
#define EE 640000
#define LL 5

typedef __attribute__((ext_vector_type(8))) short short8;
typedef __attribute__((ext_vector_type(4))) short short4v;
typedef __attribute__((ext_vector_type(4))) float f32x4;

static __device__ __forceinline__ short f2bf(float f) {
    // round-to-nearest-even fp32 -> bf16 (finite values only)
    unsigned u = __builtin_bit_cast(unsigned, f);
    unsigned r = (u + 0x7fffu + ((u >> 16) & 1u)) >> 16;
    return (short)r;
}

// ---------------------------------------------------------------------------
// Fold BN (eval mode) into weights/biases; pack weights bf16 in [n][k] layout
// (k contiguous) so MFMA B-fragments are single 16B loads.
// W1 ref layout: [L][128][256] (k-major rows). W2 ref: [L][256][128].
// ---------------------------------------------------------------------------
__global__ __launch_bounds__(256) void prep(
    const float* __restrict__ W1, const float* __restrict__ b1,
    const float* __restrict__ g1, const float* __restrict__ bb1,
    const float* __restrict__ m1, const float* __restrict__ v1,
    const float* __restrict__ W2, const float* __restrict__ b2,
    const float* __restrict__ g2, const float* __restrict__ bb2,
    const float* __restrict__ m2, const float* __restrict__ v2,
    short* __restrict__ W1p, float* __restrict__ b1e,
    short* __restrict__ W2p, float* __restrict__ b2e)
{
    int id = blockIdx.x * 256 + threadIdx.x;   // total 5*256*128 = 163840
    if (id < LL * HH * DD) {
        int l = id >> 15;
        int rem = id & 32767;
        // W1p[l][n][k], n in [0,256), k in [0,128)
        {
            int n = rem >> 7, k = rem & 127;
            float s = g1[l * HH + n] * rsqrtf(v1[l * HH + n] + 1e-5f);
            W1p[id] = f2bf(W1[l * 32768 + k * HH + n] * s);
        }
        // W2p[l][n2][k2], n2 in [0,128), k2 in [0,256)
        {
            int n2 = rem >> 8, k2 = rem & 255;
            float s = g2[l * DD + n2] * rsqrtf(v2[l * DD + n2] + 1e-5f);
            W2p[id] = f2bf(W2[l * 32768 + k2 * DD + n2] * s);
        }
    }
    if (id < LL * HH) {
        float s = g1[id] * rsqrtf(v1[id] + 1e-5f);
        b1e[id] = (b1[id] - m1[id]) * s + bb1[id];
    }
    if (id < LL * DD) {
        float s = g2[id] * rsqrtf(v2[id] + 1e-5f);
        b2e[id] = (b2[id] - m2[id]) * s + bb2[id];
    }
}

// agg = x  (self term init for layer 0)
__global__ __launch_bounds__(256) void copy_x(const float* __restrict__ x,
                                              float* __restrict__ agg)
{
    int idx = blockIdx.x * 256 + threadIdx.x;   // < N*32
    reinterpret_cast<float4*>(agg)[idx] = reinterpret_cast<const float4*>(x)[idx];
}

// agg[dst] += h[src] : 32 threads per edge, float4 each, fp32 atomics
__global__ __launch_bounds__(256) void agg_edges(const float* __restrict__ h,
                                                 const int* __restrict__ src,
                                                 const int* __restrict__ dst,
                                                 float* agg)
{
    int t = blockIdx.x * 256 + threadIdx.x;   // < E*32 = 20,480,000
    int e = t >> 5;
    int j = (t & 31) * 4;
    int s = src[e], d = dst[e];
    float4 v = *reinterpret_cast<const float4*>(&h[(size_t)s * DD + j]);
    float* out = &agg[(size_t)d * DD + j];
    atomicAdd(out + 0, v.x);
    atomicAdd(out + 1, v.y);
    atomicAdd(out + 2, v.z);
    atomicAdd(out + 3, v.w);
}

// ---------------------------------------------------------------------------
// Fused MLP: h_out = bn2(relu(bn1(agg @ W1 + b1)) @ W2 + b2) [+relu]
// Block = 256 threads (4 waves) handles 64 rows.
// GEMM1: waves split 256 cols into 4x64; GEMM2: split 128 cols into 4x32.
// z round-trips through LDS (MFMA D-layout -> A-layout).
// ---------------------------------------------------------------------------
__global__ __launch_bounds__(256) void mlp(
    float* agg,                       // read 64 rows, (optionally) rewritten in epilogue
    const short* __restrict__ W1l,    // [256][128] bf16
    const float* __restrict__ b1l,    // [256]
    const short* __restrict__ W2l,    // [128][256] bf16
    const float* __restrict__ b2l,    // [128]
    float* hout, int writeAgg, int reluOut)
{
    __shared__ __attribute__((aligned(16))) short sA[64 * 136];   // 64 x (128+8) bf16
    __shared__ __attribute__((aligned(16))) short sZ[64 * 264];   // 64 x (256+8) bf16

    const int tid = threadIdx.x;
    const int r0 = blockIdx.x * 64;
    const int wave = tid >> 6;
    const int lane = tid & 63;
    const int quad = lane >> 4;
    const int l16 = lane & 15;

    // ---- Stage A: load agg tile (fp32) -> sA (bf16) ----
    {
        int rr = tid >> 5;          // 0..7
        int c4 = (tid & 31) * 4;    // 0,4,...,124
        for (int i = 0; i < 8; ++i) {
            int row = i * 8 + rr;
            int grow = r0 + row;
            float4 v;
            if (grow < ND) v = *reinterpret_cast<const float4*>(&agg[(size_t)grow * DD + c4]);
            else { v.x = 0.f; v.y = 0.f; v.z = 0.f; v.w = 0.f; }
            short4v s;
            s.x = f2bf(v.x); s.y = f2bf(v.y); s.z = f2bf(v.z); s.w = f2bf(v.w);
            *reinterpret_cast<short4v*>(&sA[row * 136 + c4]) = s;
        }
    }
    __syncthreads();

    // ---- Stage B: GEMM1 tile, wave covers all 64 rows x 64 cols ----
    const f32x4 zero4 = {0.f, 0.f, 0.f, 0.f};
    f32x4 acc1[4][4];
    for (int rt = 0; rt < 4; ++rt)
        for (int ct = 0; ct < 4; ++ct) acc1[rt][ct] = zero4;

    const int cbase = wave * 64;
    for (int ks = 0; ks < 4; ++ks) {
        int kofs = ks * 32 + quad * 8;
        short8 a[4], b[4];
        for (int rt = 0; rt < 4; ++rt)
            a[rt] = *reinterpret_cast<const short8*>(&sA[(rt * 16 + l16) * 136 + kofs]);
        for (int ct = 0; ct < 4; ++ct)
            b[ct] = *reinterpret_cast<const short8*>(&W1l[(cbase + ct * 16 + l16) * DD + kofs]);
        for (int rt = 0; rt < 4; ++rt)
            for (int ct = 0; ct < 4; ++ct)
                acc1[rt][ct] = __builtin_amdgcn_mfma_f32_16x16x32_bf16(
                    a[rt], b[ct], acc1[rt][ct], 0, 0, 0);
    }

    // ---- Stage C: bias + ReLU -> sZ (bf16, A-operand layout = row major) ----
    for (int ct = 0; ct < 4; ++ct) {
        int col = cbase + ct * 16 + l16;
        float bias = b1l[col];
        for (int rt = 0; rt < 4; ++rt) {
            for (int r = 0; r < 4; ++r) {
                int row = rt * 16 + quad * 4 + r;
                float v = acc1[rt][ct][r] + bias;
                v = fmaxf(v, 0.f);
                sZ[row * 264 + col] = f2bf(v);
            }
        }
    }
    __syncthreads();

    // ---- Stage D: GEMM2, wave covers all 64 rows x 32 cols ----
    f32x4 acc2[4][2];
    for (int rt = 0; rt < 4; ++rt)
        for (int ct = 0; ct < 2; ++ct) acc2[rt][ct] = zero4;

    const int c2 = wave * 32;
    for (int ks = 0; ks < 8; ++ks) {
        int kofs = ks * 32 + quad * 8;
        short8 a[4], b[2];
        for (int rt = 0; rt < 4; ++rt)
            a[rt] = *reinterpret_cast<const short8*>(&sZ[(rt * 16 + l16) * 264 + kofs]);
        for (int ct = 0; ct < 2; ++ct)
            b[ct] = *reinterpret_cast<const short8*>(&W2l[(c2 + ct * 16 + l16) * HH + kofs]);
        for (int rt = 0; rt < 4; ++rt)
            for (int ct = 0; ct < 2; ++ct)
                acc2[rt][ct] = __builtin_amdgcn_mfma_f32_16x16x32_bf16(
                    a[rt], b[ct], acc2[rt][ct], 0, 0, 0);
    }

    // ---- Stage E: bias (+ReLU) -> hout (and agg for next layer's self term) ----
    for (int ct = 0; ct < 2; ++ct) {
        int col = c2 + ct * 16 + l16;
        float bias = b2l[col];
        for (int rt = 0; rt < 4; ++rt) {
            for (int r = 0; r < 4; ++r) {
                int grow = r0 + rt * 16 + quad * 4 + r;
                if (grow < ND) {
                    float v = acc2[rt][ct][r] + bias;
                    if (reluOut) v = fmaxf(v, 0.f);
                    hout[(size_t)grow * DD + col] = v;
                    if (writeAgg) agg[(size_t)grow * DD + col] = v;
                }
            }
        }
    }
}

extern "C" void kernel_launch(void* const* d_in, const int* in_sizes, int n_in,
                              void* d_out, int out_size, void* d_ws, size_t ws_size,
                              hipStream_t stream)
{
    const float* x  = (const float*)d_in[0];
    const int* ei   = (const int*)d_in[1];
    const int* src  = ei;
    const int* dst  = ei + EE;
    const float* W1 = (const float*)d_in[2];
    const float* b1 = (const float*)d_in[3];
    const float* g1 = (const float*)d_in[4];
    const float* bb1= (const float*)d_in[5];
    const float* m1 = (const float*)d_in[6];
    const float* v1 = (const float*)d_in[7];
    const float* W2 = (const float*)d_in[8];
    const float* b2 = (const float*)d_in[9];
    const float* g2 = (const float*)d_in[10];
    const float* bb2= (const float*)d_in[11];
    const float* m2 = (const float*)d_in[12];
    const float* v2 = (const float*)d_in[13];

    char* w    = (char*)d_ws;
    float* agg = (float*)w;                                   // 51,200,000 B
    short* W1p = (short*)(w + 51200000);                      // 327,680 B
    short* W2p = (short*)(w + 51200000 + 327680);             // 327,680 B
    float* b1e = (float*)(w + 51200000 + 655360);             // 5,120 B
    float* b2e = (float*)(w + 51200000 + 655360 + 5120);      // 2,560 B
    float* hbuf = (float*)d_out;   // reuse output buffer as the h ping buffer
    float* out  = (float*)d_out;

    prep<<<640, 256, 0, stream>>>(W1, b1, g1, bb1, m1, v1,
                                  W2, b2, g2, bb2, m2, v2,
                                  W1p, b1e, W2p, b2e);
    copy_x<<<12500, 256, 0, stream>>>(x, agg);

    for (int l = 0; l < LL; ++l) {
        const float* hsrc = (l == 0) ? x : hbuf;
        agg_edges<<<80000, 256, 0, stream>>>(hsrc, src, dst, agg);
        mlp<<<1563, 256, 0, stream>>>(agg,
                                      W1p + l * 32768, b1e + l * HH,
                                      W2p + l * 32768, b2e + l * DD,
                                      (l == LL - 1) ? out : hbuf,
                                      (l < LL - 1) ? 1 : 0,
                                      (l < LL - 1) ? 1 : 0);
    }
}

// Round 2
// 777.823 us; speedup vs baseline: 7.4379x; 7.4379x over previous
//
#include <hip/hip_runtime.h>

#define ND 100000
#define DD 128
#define HH 256
#define EE 640000
#define LL 5

typedef __attribute__((ext_vector_type(8))) short short8;
typedef __attribute__((ext_vector_type(4))) short short4v;
typedef __attribute__((ext_vector_type(4))) float f32x4;

static __device__ __forceinline__ short f2bf(float f) {
    unsigned u = __builtin_bit_cast(unsigned, f);
    unsigned r = (u + 0x7fffu + ((u >> 16) & 1u)) >> 16;
    return (short)r;
}

// ---------------------------------------------------------------------------
// Fold BN into weights/biases; pack weights bf16 [n][k] (k contiguous).
// ---------------------------------------------------------------------------
__global__ __launch_bounds__(256) void prep(
    const float* __restrict__ W1, const float* __restrict__ b1,
    const float* __restrict__ g1, const float* __restrict__ bb1,
    const float* __restrict__ m1, const float* __restrict__ v1,
    const float* __restrict__ W2, const float* __restrict__ b2,
    const float* __restrict__ g2, const float* __restrict__ bb2,
    const float* __restrict__ m2, const float* __restrict__ v2,
    short* __restrict__ W1p, float* __restrict__ b1e,
    short* __restrict__ W2p, float* __restrict__ b2e)
{
    int id = blockIdx.x * 256 + threadIdx.x;
    if (id < LL * HH * DD) {
        int l = id >> 15;
        int rem = id & 32767;
        {
            int n = rem >> 7, k = rem & 127;
            float s = g1[l * HH + n] * rsqrtf(v1[l * HH + n] + 1e-5f);
            W1p[id] = f2bf(W1[l * 32768 + k * HH + n] * s);
        }
        {
            int n2 = rem >> 8, k2 = rem & 255;
            float s = g2[l * DD + n2] * rsqrtf(v2[l * DD + n2] + 1e-5f);
            W2p[id] = f2bf(W2[l * 32768 + k2 * DD + n2] * s);
        }
    }
    if (id < LL * HH) {
        float s = g1[id] * rsqrtf(v1[id] + 1e-5f);
        b1e[id] = (b1[id] - m1[id]) * s + bb1[id];
    }
    if (id < LL * DD) {
        float s = g2[id] * rsqrtf(v2[id] + 1e-5f);
        b2e[id] = (b2[id] - m2[id]) * s + bb2[id];
    }
}

// ---------------------------------------------------------------------------
// CSR build (edge structure shared by all 5 layers; ws re-poisoned each call
// so counters must be zeroed here every time).
// ---------------------------------------------------------------------------
__global__ __launch_bounds__(256) void zero_counts(int* __restrict__ p /* cnt+cursor, contiguous */)
{
    int i = blockIdx.x * 256 + threadIdx.x;   // int4 granularity, 2*ND ints total
    if (i * 4 < 2 * ND) {
        int rem = 2 * ND - i * 4;
        if (rem >= 4) reinterpret_cast<int4*>(p)[i] = make_int4(0, 0, 0, 0);
        else for (int j = 0; j < rem; ++j) p[i * 4 + j] = 0;
    }
}

__global__ __launch_bounds__(256) void hist(const int* __restrict__ dst, int* __restrict__ cnt)
{
    int e = blockIdx.x * 256 + threadIdx.x;
    if (e < EE) atomicAdd(&cnt[dst[e]], 1);
}

// single-block scan, 1024 threads x 4 elements/iter
__global__ __launch_bounds__(1024) void scan_deg(const int* __restrict__ cnt,
                                                 int* __restrict__ rowstart)
{
    __shared__ int buf[1024];
    __shared__ int carry_s;
    int tid = threadIdx.x;
    if (tid == 0) { carry_s = 0; rowstart[0] = 0; }
    __syncthreads();
    for (int base = 0; base < ND; base += 4096) {
        int carry = carry_s;
        int idx = base + tid * 4;
        int v0 = 0, v1 = 0, v2 = 0, v3 = 0;
        if (idx + 3 < ND) {
            int4 t = *reinterpret_cast<const int4*>(&cnt[idx]);
            v0 = t.x; v1 = t.y; v2 = t.z; v3 = t.w;
        } else {
            if (idx     < ND) v0 = cnt[idx];
            if (idx + 1 < ND) v1 = cnt[idx + 1];
            if (idx + 2 < ND) v2 = cnt[idx + 2];
            if (idx + 3 < ND) v3 = cnt[idx + 3];
        }
        int p1 = v0 + v1, p2 = p1 + v2, p3 = p2 + v3;
        buf[tid] = p3;
        __syncthreads();
        int sum = p3;
        for (int off = 1; off < 1024; off <<= 1) {
            int t = (tid >= off) ? buf[tid - off] : 0;
            __syncthreads();
            sum += t;
            buf[tid] = sum;
            __syncthreads();
        }
        int excl = carry + sum - p3;
        if (idx     < ND) rowstart[idx + 1] = excl + v0;
        if (idx + 1 < ND) rowstart[idx + 2] = excl + p1;
        if (idx + 2 < ND) rowstart[idx + 3] = excl + p2;
        if (idx + 3 < ND) rowstart[idx + 4] = excl + p3;
        __syncthreads();
        if (tid == 0) carry_s = carry + buf[1023];
        __syncthreads();
    }
}

__global__ __launch_bounds__(256) void fill_csr(const int* __restrict__ src,
                                                const int* __restrict__ dst,
                                                const int* __restrict__ rowstart,
                                                int* __restrict__ cursor,
                                                int* __restrict__ csr)
{
    int e = blockIdx.x * 256 + threadIdx.x;
    if (e < EE) {
        int d = dst[e];
        int p = atomicAdd(&cursor[d], 1);
        csr[rowstart[d] + p] = src[e];
    }
}

// ---------------------------------------------------------------------------
// agg[n] = h[n] + sum_{j in in(n)} h[j]   — 32 lanes per node, float4/lane
// ---------------------------------------------------------------------------
__global__ __launch_bounds__(256) void agg_gather(const float* __restrict__ h,
                                                  const int* __restrict__ rowstart,
                                                  const int* __restrict__ csr,
                                                  float* __restrict__ agg)
{
    int g = blockIdx.x * 256 + threadIdx.x;
    int node = g >> 5;
    if (node >= ND) return;
    int c = (g & 31) * 4;
    int s = rowstart[node], e = rowstart[node + 1];
    float4 acc = *reinterpret_cast<const float4*>(&h[(size_t)node * DD + c]);
    int i = s;
    for (; i + 1 < e; i += 2) {
        int s0 = csr[i], s1 = csr[i + 1];
        float4 a = *reinterpret_cast<const float4*>(&h[(size_t)s0 * DD + c]);
        float4 b = *reinterpret_cast<const float4*>(&h[(size_t)s1 * DD + c]);
        acc.x += a.x + b.x; acc.y += a.y + b.y;
        acc.z += a.z + b.z; acc.w += a.w + b.w;
    }
    if (i < e) {
        int s0 = csr[i];
        float4 a = *reinterpret_cast<const float4*>(&h[(size_t)s0 * DD + c]);
        acc.x += a.x; acc.y += a.y; acc.z += a.z; acc.w += a.w;
    }
    *reinterpret_cast<float4*>(&agg[(size_t)node * DD + c]) = acc;
}

// ---------------------------------------------------------------------------
// Fused MLP (unchanged structure from R0, agg write-back removed)
// ---------------------------------------------------------------------------
__global__ __launch_bounds__(256) void mlp(
    const float* __restrict__ agg,
    const short* __restrict__ W1l,    // [256][128] bf16
    const float* __restrict__ b1l,
    const short* __restrict__ W2l,    // [128][256] bf16
    const float* __restrict__ b2l,
    float* __restrict__ hout, int reluOut)
{
    __shared__ __attribute__((aligned(16))) short sA[64 * 136];
    __shared__ __attribute__((aligned(16))) short sZ[64 * 264];

    const int tid = threadIdx.x;
    const int r0 = blockIdx.x * 64;
    const int wave = tid >> 6;
    const int lane = tid & 63;
    const int quad = lane >> 4;
    const int l16 = lane & 15;

    {
        int rr = tid >> 5;
        int c4 = (tid & 31) * 4;
        for (int i = 0; i < 8; ++i) {
            int row = i * 8 + rr;
            int grow = r0 + row;
            float4 v;
            if (grow < ND) v = *reinterpret_cast<const float4*>(&agg[(size_t)grow * DD + c4]);
            else { v.x = 0.f; v.y = 0.f; v.z = 0.f; v.w = 0.f; }
            short4v s;
            s.x = f2bf(v.x); s.y = f2bf(v.y); s.z = f2bf(v.z); s.w = f2bf(v.w);
            *reinterpret_cast<short4v*>(&sA[row * 136 + c4]) = s;
        }
    }
    __syncthreads();

    const f32x4 zero4 = {0.f, 0.f, 0.f, 0.f};
    f32x4 acc1[4][4];
    for (int rt = 0; rt < 4; ++rt)
        for (int ct = 0; ct < 4; ++ct) acc1[rt][ct] = zero4;

    const int cbase = wave * 64;
    for (int ks = 0; ks < 4; ++ks) {
        int kofs = ks * 32 + quad * 8;
        short8 a[4], b[4];
        for (int rt = 0; rt < 4; ++rt)
            a[rt] = *reinterpret_cast<const short8*>(&sA[(rt * 16 + l16) * 136 + kofs]);
        for (int ct = 0; ct < 4; ++ct)
            b[ct] = *reinterpret_cast<const short8*>(&W1l[(cbase + ct * 16 + l16) * DD + kofs]);
        for (int rt = 0; rt < 4; ++rt)
            for (int ct = 0; ct < 4; ++ct)
                acc1[rt][ct] = __builtin_amdgcn_mfma_f32_16x16x32_bf16(
                    a[rt], b[ct], acc1[rt][ct], 0, 0, 0);
    }

    for (int ct = 0; ct < 4; ++ct) {
        int col = cbase + ct * 16 + l16;
        float bias = b1l[col];
        for (int rt = 0; rt < 4; ++rt) {
            for (int r = 0; r < 4; ++r) {
                int row = rt * 16 + quad * 4 + r;
                float v = acc1[rt][ct][r] + bias;
                v = fmaxf(v, 0.f);
                sZ[row * 264 + col] = f2bf(v);
            }
        }
    }
    __syncthreads();

    f32x4 acc2[4][2];
    for (int rt = 0; rt < 4; ++rt)
        for (int ct = 0; ct < 2; ++ct) acc2[rt][ct] = zero4;

    const int c2 = wave * 32;
    for (int ks = 0; ks < 8; ++ks) {
        int kofs = ks * 32 + quad * 8;
        short8 a[4], b[2];
        for (int rt = 0; rt < 4; ++rt)
            a[rt] = *reinterpret_cast<const short8*>(&sZ[(rt * 16 + l16) * 264 + kofs]);
        for (int ct = 0; ct < 2; ++ct)
            b[ct] = *reinterpret_cast<const short8*>(&W2l[(c2 + ct * 16 + l16) * HH + kofs]);
        for (int rt = 0; rt < 4; ++rt)
            for (int ct = 0; ct < 2; ++ct)
                acc2[rt][ct] = __builtin_amdgcn_mfma_f32_16x16x32_bf16(
                    a[rt], b[ct], acc2[rt][ct], 0, 0, 0);
    }

    for (int ct = 0; ct < 2; ++ct) {
        int col = c2 + ct * 16 + l16;
        float bias = b2l[col];
        for (int rt = 0; rt < 4; ++rt) {
            for (int r = 0; r < 4; ++r) {
                int grow = r0 + rt * 16 + quad * 4 + r;
                if (grow < ND) {
                    float v = acc2[rt][ct][r] + bias;
                    if (reluOut) v = fmaxf(v, 0.f);
                    hout[(size_t)grow * DD + col] = v;
                }
            }
        }
    }
}

extern "C" void kernel_launch(void* const* d_in, const int* in_sizes, int n_in,
                              void* d_out, int out_size, void* d_ws, size_t ws_size,
                              hipStream_t stream)
{
    const float* x  = (const float*)d_in[0];
    const int* ei   = (const int*)d_in[1];
    const int* src  = ei;
    const int* dst  = ei + EE;
    const float* W1 = (const float*)d_in[2];
    const float* b1 = (const float*)d_in[3];
    const float* g1 = (const float*)d_in[4];
    const float* bb1= (const float*)d_in[5];
    const float* m1 = (const float*)d_in[6];
    const float* v1 = (const float*)d_in[7];
    const float* W2 = (const float*)d_in[8];
    const float* b2 = (const float*)d_in[9];
    const float* g2 = (const float*)d_in[10];
    const float* bb2= (const float*)d_in[11];
    const float* m2 = (const float*)d_in[12];
    const float* v2 = (const float*)d_in[13];

    char* w    = (char*)d_ws;
    float* agg   = (float*)w;                                 // 51,200,000
    short* W1p   = (short*)(w + 51200000);                    //    327,680
    short* W2p   = (short*)(w + 51527680);                    //    327,680
    float* b1e   = (float*)(w + 51855360);                    //      5,120
    float* b2e   = (float*)(w + 51860480);                    //      2,560
    int*   cnt   = (int*)  (w + 51863040);                    //    400,000 (cnt)
    int*   cursor= (int*)  (w + 52263040);                    //    400,000 (cursor, contiguous after cnt)
    int*   rowst = (int*)  (w + 52663040);                    //    400,016
    int*   csr   = (int*)  (w + 53063056);                    //  2,560,000
    float* hbuf  = (float*)d_out;
    float* out   = (float*)d_out;

    prep<<<640, 256, 0, stream>>>(W1, b1, g1, bb1, m1, v1,
                                  W2, b2, g2, bb2, m2, v2,
                                  W1p, b1e, W2p, b2e);
    zero_counts<<<196, 256, 0, stream>>>(cnt);   // zeroes cnt+cursor (contiguous)
    hist<<<2500, 256, 0, stream>>>(dst, cnt);
    scan_deg<<<1, 1024, 0, stream>>>(cnt, rowst);
    fill_csr<<<2500, 256, 0, stream>>>(src, dst, rowst, cursor, csr);

    for (int l = 0; l < LL; ++l) {
        const float* hsrc = (l == 0) ? x : hbuf;
        agg_gather<<<12500, 256, 0, stream>>>(hsrc, rowst, csr, agg);
        mlp<<<1563, 256, 0, stream>>>(agg,
                                      W1p + l * 32768, b1e + l * HH,
                                      W2p + l * 32768, b2e + l * DD,
                                      (l == LL - 1) ? out : hbuf,
                                      (l < LL - 1) ? 1 : 0);
    }
}

// Round 3
// 573.557 us; speedup vs baseline: 10.0868x; 1.3561x over previous
//
#include <hip/hip_runtime.h>

#define ND 100000
#define DD 128
#define HH 256
#define EE 640000
#define LL 5

typedef __attribute__((ext_vector_type(8))) short short8;
typedef __attribute__((ext_vector_type(4))) short short4v;
typedef __attribute__((ext_vector_type(4))) float f32x4;

static __device__ __forceinline__ short f2bf(float f) {
    unsigned u = __builtin_bit_cast(unsigned, f);
    unsigned r = (u + 0x7fffu + ((u >> 16) & 1u)) >> 16;
    return (short)r;
}
static __device__ __forceinline__ float bf2f(short s) {
    unsigned u = ((unsigned)(unsigned short)s) << 16;
    return __builtin_bit_cast(float, u);
}

// ---------------------------------------------------------------------------
// Fold BN into weights/biases; pack weights bf16 [n][k] (k contiguous).
// ---------------------------------------------------------------------------
__global__ __launch_bounds__(256) void prep(
    const float* __restrict__ W1, const float* __restrict__ b1,
    const float* __restrict__ g1, const float* __restrict__ bb1,
    const float* __restrict__ m1, const float* __restrict__ v1,
    const float* __restrict__ W2, const float* __restrict__ b2,
    const float* __restrict__ g2, const float* __restrict__ bb2,
    const float* __restrict__ m2, const float* __restrict__ v2,
    short* __restrict__ W1p, float* __restrict__ b1e,
    short* __restrict__ W2p, float* __restrict__ b2e)
{
    int id = blockIdx.x * 256 + threadIdx.x;
    if (id < LL * HH * DD) {
        int l = id >> 15;
        int rem = id & 32767;
        {
            int n = rem >> 7, k = rem & 127;
            float s = g1[l * HH + n] * rsqrtf(v1[l * HH + n] + 1e-5f);
            W1p[id] = f2bf(W1[l * 32768 + k * HH + n] * s);
        }
        {
            int n2 = rem >> 8, k2 = rem & 255;
            float s = g2[l * DD + n2] * rsqrtf(v2[l * DD + n2] + 1e-5f);
            W2p[id] = f2bf(W2[l * 32768 + k2 * DD + n2] * s);
        }
    }
    if (id < LL * HH) {
        float s = g1[id] * rsqrtf(v1[id] + 1e-5f);
        b1e[id] = (b1[id] - m1[id]) * s + bb1[id];
    }
    if (id < LL * DD) {
        float s = g2[id] * rsqrtf(v2[id] + 1e-5f);
        b2e[id] = (b2[id] - m2[id]) * s + bb2[id];
    }
}

// x (fp32) -> hbuf (bf16)
__global__ __launch_bounds__(256) void conv_x(const float* __restrict__ x,
                                              short* __restrict__ hb)
{
    int i = blockIdx.x * 256 + threadIdx.x;   // exactly ND*DD/4 threads
    float4 v = reinterpret_cast<const float4*>(x)[i];
    short4v s;
    s.x = f2bf(v.x); s.y = f2bf(v.y); s.z = f2bf(v.z); s.w = f2bf(v.w);
    reinterpret_cast<short4v*>(hb)[i] = s;
}

// ---------------------------------------------------------------------------
// CSR build (ws re-poisoned each call -> rebuild every time)
// ---------------------------------------------------------------------------
__global__ __launch_bounds__(256) void zero_counts(int* __restrict__ p)  // cnt+cursor
{
    int i = blockIdx.x * 256 + threadIdx.x;
    if (i * 4 < 2 * ND) {
        int rem = 2 * ND - i * 4;
        if (rem >= 4) reinterpret_cast<int4*>(p)[i] = make_int4(0, 0, 0, 0);
        else for (int j = 0; j < rem; ++j) p[i * 4 + j] = 0;
    }
}

__global__ __launch_bounds__(256) void hist(const int* __restrict__ dst, int* __restrict__ cnt)
{
    int e = blockIdx.x * 256 + threadIdx.x;
    if (e < EE) atomicAdd(&cnt[dst[e]], 1);
}

// per-block inclusive scan of cnt (in place) + block totals
__global__ __launch_bounds__(256) void scan_block(int* __restrict__ cnt, int* __restrict__ bsum)
{
    __shared__ int buf[256];
    int tid = threadIdx.x;
    int idx = blockIdx.x * 256 + tid;
    int v = (idx < ND) ? cnt[idx] : 0;
    buf[tid] = v;
    __syncthreads();
    int sum = v;
    for (int off = 1; off < 256; off <<= 1) {
        int t = (tid >= off) ? buf[tid - off] : 0;
        __syncthreads();
        sum += t;
        buf[tid] = sum;
        __syncthreads();
    }
    if (idx < ND) cnt[idx] = sum;
    if (tid == 255) bsum[blockIdx.x] = sum;
}

__global__ __launch_bounds__(512) void scan_bsum(const int* __restrict__ bsum,
                                                 int* __restrict__ boffs)
{
    __shared__ int buf[512];
    int tid = threadIdx.x;
    int v = (tid < 391) ? bsum[tid] : 0;
    buf[tid] = v;
    __syncthreads();
    int sum = v;
    for (int off = 1; off < 512; off <<= 1) {
        int t = (tid >= off) ? buf[tid - off] : 0;
        __syncthreads();
        sum += t;
        buf[tid] = sum;
        __syncthreads();
    }
    if (tid < 391) boffs[tid] = sum - v;   // exclusive block offset
}

__global__ __launch_bounds__(256) void apply_offs(const int* __restrict__ cnt,
                                                  const int* __restrict__ boffs,
                                                  int* __restrict__ rowst)
{
    int idx = blockIdx.x * 256 + threadIdx.x;
    if (idx < ND) rowst[idx + 1] = cnt[idx] + boffs[blockIdx.x];
    if (idx == 0) rowst[0] = 0;
}

__global__ __launch_bounds__(256) void fill_csr(const int* __restrict__ src,
                                                const int* __restrict__ dst,
                                                const int* __restrict__ rowstart,
                                                int* __restrict__ cursor,
                                                int* __restrict__ csr)
{
    int e = blockIdx.x * 256 + threadIdx.x;
    if (e < EE) {
        int d = dst[e];
        int p = atomicAdd(&cursor[d], 1);
        csr[rowstart[d] + p] = src[e];
    }
}

// ---------------------------------------------------------------------------
// aggb[n] = hb[n] + sum_{j in in(n)} hb[j]   — 16 lanes/node, short8 (16B)/lane,
// fp32 accumulate, one bf16 rounding at the end.
// ---------------------------------------------------------------------------
__global__ __launch_bounds__(256) void agg_gather(const short* __restrict__ hb,
                                                  const int* __restrict__ rowstart,
                                                  const int* __restrict__ csr,
                                                  short* __restrict__ aggb)
{
    int g = blockIdx.x * 256 + threadIdx.x;
    int node = g >> 4;
    if (node >= ND) return;
    int c = (g & 15) * 8;
    int s = rowstart[node], e = rowstart[node + 1];
    float acc[8];
    {
        short8 h0 = *reinterpret_cast<const short8*>(&hb[(size_t)node * DD + c]);
        for (int j = 0; j < 8; ++j) acc[j] = bf2f(h0[j]);
    }
    int i = s;
    for (; i + 1 < e; i += 2) {
        int s0 = csr[i], s1 = csr[i + 1];
        short8 a = *reinterpret_cast<const short8*>(&hb[(size_t)s0 * DD + c]);
        short8 b = *reinterpret_cast<const short8*>(&hb[(size_t)s1 * DD + c]);
        for (int j = 0; j < 8; ++j) acc[j] += bf2f(a[j]) + bf2f(b[j]);
    }
    if (i < e) {
        int s0 = csr[i];
        short8 a = *reinterpret_cast<const short8*>(&hb[(size_t)s0 * DD + c]);
        for (int j = 0; j < 8; ++j) acc[j] += bf2f(a[j]);
    }
    short8 o;
    for (int j = 0; j < 8; ++j) o[j] = f2bf(acc[j]);
    *reinterpret_cast<short8*>(&aggb[(size_t)node * DD + c]) = o;
}

// ---------------------------------------------------------------------------
// Fused MLP, bf16 in / bf16 out (fp32 out on last layer).
// LDS union: sA view (stride 136) for the input tile, sZ view (stride 264)
// for the z round-trip. 33,792 B -> 4 blocks/CU.
// ---------------------------------------------------------------------------
__global__ __launch_bounds__(256, 4) void mlp(
    const short* __restrict__ aggb,
    const short* __restrict__ W1l,    // [256][128] bf16
    const float* __restrict__ b1l,
    const short* __restrict__ W2l,    // [128][256] bf16
    const float* __restrict__ b2l,
    short* __restrict__ hb_out, float* __restrict__ f_out, int last)
{
    __shared__ __attribute__((aligned(16))) short sU[64 * 264];

    const int tid = threadIdx.x;
    const int r0 = blockIdx.x * 64;
    const int wave = tid >> 6;
    const int lane = tid & 63;
    const int quad = lane >> 4;
    const int l16 = lane & 15;

    // Stage A: 64x128 bf16 tile -> sU (stride 136)
    for (int p = 0; p < 4; ++p) {
        int linear = p * 256 + tid;
        int row = linear >> 4;
        int ch = (linear & 15) * 8;
        int grow = r0 + row;
        short8 v;
        if (grow < ND) v = *reinterpret_cast<const short8*>(&aggb[(size_t)grow * DD + ch]);
        else for (int j = 0; j < 8; ++j) v[j] = 0;
        *reinterpret_cast<short8*>(&sU[row * 136 + ch]) = v;
    }
    __syncthreads();

    // Stage B: GEMM1 — wave computes all 64 rows x 64 cols (cbase)
    const f32x4 zero4 = {0.f, 0.f, 0.f, 0.f};
    f32x4 acc1[4][4];
    for (int rt = 0; rt < 4; ++rt)
        for (int ct = 0; ct < 4; ++ct) acc1[rt][ct] = zero4;

    const int cbase = wave * 64;
    for (int ks = 0; ks < 4; ++ks) {
        int kofs = ks * 32 + quad * 8;
        short8 a[4], b[4];
        for (int ct = 0; ct < 4; ++ct)
            b[ct] = *reinterpret_cast<const short8*>(&W1l[(cbase + ct * 16 + l16) * DD + kofs]);
        for (int rt = 0; rt < 4; ++rt)
            a[rt] = *reinterpret_cast<const short8*>(&sU[(rt * 16 + l16) * 136 + kofs]);
        for (int rt = 0; rt < 4; ++rt)
            for (int ct = 0; ct < 4; ++ct)
                acc1[rt][ct] = __builtin_amdgcn_mfma_f32_16x16x32_bf16(
                    a[rt], b[ct], acc1[rt][ct], 0, 0, 0);
    }
    __syncthreads();   // sA view dead; sZ view reuses the same LDS

    // Stage C: bias + ReLU -> sU (stride 264, A-operand layout)
    for (int ct = 0; ct < 4; ++ct) {
        int col = cbase + ct * 16 + l16;
        float bias = b1l[col];
        for (int rt = 0; rt < 4; ++rt) {
            for (int r = 0; r < 4; ++r) {
                int row = rt * 16 + quad * 4 + r;
                float v = acc1[rt][ct][r] + bias;
                v = fmaxf(v, 0.f);
                sU[row * 264 + col] = f2bf(v);
            }
        }
    }
    __syncthreads();

    // Stage D: GEMM2 — wave computes all 64 rows x 32 cols (c2)
    f32x4 acc2[4][2];
    for (int rt = 0; rt < 4; ++rt)
        for (int ct = 0; ct < 2; ++ct) acc2[rt][ct] = zero4;

    const int c2 = wave * 32;
    for (int ks = 0; ks < 8; ++ks) {
        int kofs = ks * 32 + quad * 8;
        short8 a[4], b[2];
        for (int ct = 0; ct < 2; ++ct)
            b[ct] = *reinterpret_cast<const short8*>(&W2l[(c2 + ct * 16 + l16) * HH + kofs]);
        for (int rt = 0; rt < 4; ++rt)
            a[rt] = *reinterpret_cast<const short8*>(&sU[(rt * 16 + l16) * 264 + kofs]);
        for (int rt = 0; rt < 4; ++rt)
            for (int ct = 0; ct < 2; ++ct)
                acc2[rt][ct] = __builtin_amdgcn_mfma_f32_16x16x32_bf16(
                    a[rt], b[ct], acc2[rt][ct], 0, 0, 0);
    }

    // Stage E: bias (+ReLU) -> bf16 h, or fp32 d_out on last layer
    for (int ct = 0; ct < 2; ++ct) {
        int col = c2 + ct * 16 + l16;
        float bias = b2l[col];
        for (int rt = 0; rt < 4; ++rt) {
            for (int r = 0; r < 4; ++r) {
                int grow = r0 + rt * 16 + quad * 4 + r;
                if (grow < ND) {
                    float v = acc2[rt][ct][r] + bias;
                    if (!last) {
                        v = fmaxf(v, 0.f);
                        hb_out[(size_t)grow * DD + col] = f2bf(v);
                    } else {
                        f_out[(size_t)grow * DD + col] = v;
                    }
                }
            }
        }
    }
}

extern "C" void kernel_launch(void* const* d_in, const int* in_sizes, int n_in,
                              void* d_out, int out_size, void* d_ws, size_t ws_size,
                              hipStream_t stream)
{
    const float* x  = (const float*)d_in[0];
    const int* ei   = (const int*)d_in[1];
    const int* src  = ei;
    const int* dst  = ei + EE;
    const float* W1 = (const float*)d_in[2];
    const float* b1 = (const float*)d_in[3];
    const float* g1 = (const float*)d_in[4];
    const float* bb1= (const float*)d_in[5];
    const float* m1 = (const float*)d_in[6];
    const float* v1 = (const float*)d_in[7];
    const float* W2 = (const float*)d_in[8];
    const float* b2 = (const float*)d_in[9];
    const float* g2 = (const float*)d_in[10];
    const float* bb2= (const float*)d_in[11];
    const float* m2 = (const float*)d_in[12];
    const float* v2 = (const float*)d_in[13];

    char* w = (char*)d_ws;
    short* aggb  = (short*)w;                                 // 25,600,000
    short* hbuf  = (short*)(w + 25600000);                    // 25,600,000
    short* W1p   = (short*)(w + 51200000);                    //    327,680
    short* W2p   = (short*)(w + 51527680);                    //    327,680
    float* b1e   = (float*)(w + 51855360);                    //      5,120
    float* b2e   = (float*)(w + 51860480);                    //      2,560
    int*   cnt   = (int*)  (w + 51863040);                    //    400,000
    int*   cursor= (int*)  (w + 52263040);                    //    400,000 (contiguous after cnt)
    int*   rowst = (int*)  (w + 52663040);                    //    400,032
    int*   csr   = (int*)  (w + 53063072);                    //  2,560,000
    int*   bsum  = (int*)  (w + 55623072);                    //      1,664
    int*   boffs = (int*)  (w + 55624736);                    //      1,600
    float* out   = (float*)d_out;

    prep<<<640, 256, 0, stream>>>(W1, b1, g1, bb1, m1, v1,
                                  W2, b2, g2, bb2, m2, v2,
                                  W1p, b1e, W2p, b2e);
    zero_counts<<<196, 256, 0, stream>>>(cnt);       // cnt + cursor
    hist<<<2500, 256, 0, stream>>>(dst, cnt);
    scan_block<<<391, 256, 0, stream>>>(cnt, bsum);
    scan_bsum<<<1, 512, 0, stream>>>(bsum, boffs);
    apply_offs<<<391, 256, 0, stream>>>(cnt, boffs, rowst);
    fill_csr<<<2500, 256, 0, stream>>>(src, dst, rowst, cursor, csr);
    conv_x<<<12500, 256, 0, stream>>>(x, hbuf);

    for (int l = 0; l < LL; ++l) {
        agg_gather<<<6250, 256, 0, stream>>>(hbuf, rowst, csr, aggb);
        mlp<<<1563, 256, 0, stream>>>(aggb,
                                      W1p + l * 32768, b1e + l * HH,
                                      W2p + l * 32768, b2e + l * DD,
                                      hbuf, out, (l == LL - 1) ? 1 : 0);
    }
}

// Round 5
// 555.697 us; speedup vs baseline: 10.4110x; 1.0321x over previous
//
#include <hip/hip_runtime.h>

#define ND 100000
#define DD 128
#define HH 256
#define EE 640000
#define LL 5

typedef __attribute__((ext_vector_type(8))) short short8;
typedef __attribute__((ext_vector_type(4))) short short4v;
typedef __attribute__((ext_vector_type(4))) float f32x4;

static __device__ __forceinline__ short f2bf(float f) {
    unsigned u = __builtin_bit_cast(unsigned, f);
    unsigned r = (u + 0x7fffu + ((u >> 16) & 1u)) >> 16;
    return (short)r;
}
static __device__ __forceinline__ float bf2f(short s) {
    unsigned u = ((unsigned)(unsigned short)s) << 16;
    return __builtin_bit_cast(float, u);
}

// ---------------------------------------------------------------------------
// setup: blocks [0,640) fold BN into weights (bf16 [n][k] pack);
//        blocks [640,13140) convert x fp32 -> bf16 into hbufA;
//        blocks [13140,15640) histogram dst degrees (cnt pre-zeroed).
// ---------------------------------------------------------------------------
__global__ __launch_bounds__(256) void setup(
    const float* __restrict__ W1, const float* __restrict__ b1,
    const float* __restrict__ g1, const float* __restrict__ bb1,
    const float* __restrict__ m1, const float* __restrict__ v1,
    const float* __restrict__ W2, const float* __restrict__ b2,
    const float* __restrict__ g2, const float* __restrict__ bb2,
    const float* __restrict__ m2, const float* __restrict__ v2,
    const float* __restrict__ x, const int* __restrict__ dst,
    short* __restrict__ W1p, float* __restrict__ b1e,
    short* __restrict__ W2p, float* __restrict__ b2e,
    short* __restrict__ hb, int* __restrict__ cnt)
{
    int bx = blockIdx.x;
    int tid = threadIdx.x;
    if (bx < 640) {
        int id = bx * 256 + tid;
        if (id < LL * HH * DD) {
            int l = id >> 15;
            int rem = id & 32767;
            {
                int n = rem >> 7, k = rem & 127;
                float s = g1[l * HH + n] * rsqrtf(v1[l * HH + n] + 1e-5f);
                W1p[id] = f2bf(W1[l * 32768 + k * HH + n] * s);
            }
            {
                int n2 = rem >> 8, k2 = rem & 255;
                float s = g2[l * DD + n2] * rsqrtf(v2[l * DD + n2] + 1e-5f);
                W2p[id] = f2bf(W2[l * 32768 + k2 * DD + n2] * s);
            }
        }
        if (id < LL * HH) {
            float s = g1[id] * rsqrtf(v1[id] + 1e-5f);
            b1e[id] = (b1[id] - m1[id]) * s + bb1[id];
        }
        if (id < LL * DD) {
            float s = g2[id] * rsqrtf(v2[id] + 1e-5f);
            b2e[id] = (b2[id] - m2[id]) * s + bb2[id];
        }
    } else if (bx < 13140) {
        int i = (bx - 640) * 256 + tid;          // ND*DD/4 = 3,200,000 float4s
        float4 v = reinterpret_cast<const float4*>(x)[i];
        short4v s;
        s.x = f2bf(v.x); s.y = f2bf(v.y); s.z = f2bf(v.z); s.w = f2bf(v.w);
        reinterpret_cast<short4v*>(hb)[i] = s;
    } else {
        int e = (bx - 13140) * 256 + tid;
        if (e < EE) atomicAdd(&cnt[dst[e]], 1);
    }
}

__global__ __launch_bounds__(256) void zero_counts(int* __restrict__ p)  // cnt+cursor
{
    int i = blockIdx.x * 256 + threadIdx.x;
    if (i * 4 < 2 * ND) {
        int rem = 2 * ND - i * 4;
        if (rem >= 4) reinterpret_cast<int4*>(p)[i] = make_int4(0, 0, 0, 0);
        else for (int j = 0; j < rem; ++j) p[i * 4 + j] = 0;
    }
}

// per-block inclusive scan of cnt (in place) + block totals
__global__ __launch_bounds__(256) void scan_block(int* __restrict__ cnt, int* __restrict__ bsum)
{
    __shared__ int buf[256];
    int tid = threadIdx.x;
    int idx = blockIdx.x * 256 + tid;
    int v = (idx < ND) ? cnt[idx] : 0;
    buf[tid] = v;
    __syncthreads();
    int sum = v;
    for (int off = 1; off < 256; off <<= 1) {
        int t = (tid >= off) ? buf[tid - off] : 0;
        __syncthreads();
        sum += t;
        buf[tid] = sum;
        __syncthreads();
    }
    if (idx < ND) cnt[idx] = sum;
    if (tid == 255) bsum[blockIdx.x] = sum;
}

__global__ __launch_bounds__(512) void scan_bsum(const int* __restrict__ bsum,
                                                 int* __restrict__ boffs)
{
    __shared__ int buf[512];
    int tid = threadIdx.x;
    int v = (tid < 391) ? bsum[tid] : 0;
    buf[tid] = v;
    __syncthreads();
    int sum = v;
    for (int off = 1; off < 512; off <<= 1) {
        int t = (tid >= off) ? buf[tid - off] : 0;
        __syncthreads();
        sum += t;
        buf[tid] = sum;
        __syncthreads();
    }
    if (tid < 391) boffs[tid] = sum - v;   // exclusive block offset
}

__global__ __launch_bounds__(256) void apply_offs(const int* __restrict__ cnt,
                                                  const int* __restrict__ boffs,
                                                  int* __restrict__ rowst)
{
    int idx = blockIdx.x * 256 + threadIdx.x;
    if (idx < ND) rowst[idx + 1] = cnt[idx] + boffs[blockIdx.x];
    if (idx == 0) rowst[0] = 0;
}

__global__ __launch_bounds__(256) void fill_csr(const int* __restrict__ src,
                                                const int* __restrict__ dst,
                                                const int* __restrict__ rowstart,
                                                int* __restrict__ cursor,
                                                int* __restrict__ csr)
{
    int e = blockIdx.x * 256 + threadIdx.x;
    if (e < EE) {
        int d = dst[e];
        int p = atomicAdd(&cursor[d], 1);
        csr[rowstart[d] + p] = src[e];
    }
}

// ---------------------------------------------------------------------------
// Fused GIN layer: gather(64 rows) -> LDS -> zT = W1 x agg -> LDS -> hT = W2 x z
// hb_in and hb_out MUST be distinct buffers (cross-block WAR hazard otherwise
// — R3 failed exactly this way; dispatch order across blocks is undefined).
// Transposed-operand GEMMs: A-op = weights [out][k], B-op = activations
// [node][k]; D-layout gives lane 4 consecutive out-cols -> vector stores.
// LDS union: gather tile view stride 136, z view stride 264 (33,792 B).
// ---------------------------------------------------------------------------
__global__ __launch_bounds__(256, 4) void layer_fused(
    const short* __restrict__ hb_in,
    const int* __restrict__ rowst,
    const int* __restrict__ csr,
    const short* __restrict__ W1l,    // [256][128] bf16
    const float* __restrict__ b1l,    // [256]
    const short* __restrict__ W2l,    // [128][256] bf16
    const float* __restrict__ b2l,    // [128]
    short* __restrict__ hb_out, float* __restrict__ f_out, int last)
{
    __shared__ __attribute__((aligned(16))) short sU[64 * 264];

    const int tid = threadIdx.x;
    const int r0 = blockIdx.x * 64;
    const int wave = tid >> 6;
    const int lane = tid & 63;
    const int quad = lane >> 4;
    const int l16 = lane & 15;

    // ---- Stage A: fused neighbor gather -> sU (stride 136) ----
    for (int p = 0; p < 4; ++p) {
        int t = p * 256 + tid;          // 0..1023 = 64 rows x 16 chunks
        int row = t >> 4;
        int ch = (t & 15) * 8;
        int grow = r0 + row;
        float acc[8];
        if (grow < ND) {
            short8 h0 = *reinterpret_cast<const short8*>(&hb_in[(size_t)grow * DD + ch]);
            for (int j = 0; j < 8; ++j) acc[j] = bf2f(h0[j]);
            int s = rowst[grow], e = rowst[grow + 1];
            int i = s;
            for (; i + 1 < e; i += 2) {
                int s0 = csr[i], s1 = csr[i + 1];
                short8 a = *reinterpret_cast<const short8*>(&hb_in[(size_t)s0 * DD + ch]);
                short8 b = *reinterpret_cast<const short8*>(&hb_in[(size_t)s1 * DD + ch]);
                for (int j = 0; j < 8; ++j) acc[j] += bf2f(a[j]) + bf2f(b[j]);
            }
            if (i < e) {
                short8 a = *reinterpret_cast<const short8*>(&hb_in[(size_t)csr[i] * DD + ch]);
                for (int j = 0; j < 8; ++j) acc[j] += bf2f(a[j]);
            }
        } else {
            for (int j = 0; j < 8; ++j) acc[j] = 0.f;
        }
        short8 o;
        for (int j = 0; j < 8; ++j) o[j] = f2bf(acc[j]);
        *reinterpret_cast<short8*>(&sU[row * 136 + ch]) = o;
    }
    __syncthreads();

    // ---- Stage B: GEMM1' zT = W1(A) x agg(B); wave owns 64 zcols x 64 nodes ----
    const f32x4 zero4 = {0.f, 0.f, 0.f, 0.f};
    f32x4 acc1[4][4];   // [mt=zcol tile][nt=node tile]
    for (int mt = 0; mt < 4; ++mt)
        for (int nt = 0; nt < 4; ++nt) acc1[mt][nt] = zero4;

    const int wb = wave * 64;
    for (int ks = 0; ks < 4; ++ks) {
        int kofs = ks * 32 + quad * 8;
        short8 aw[4], bn[4];
        for (int mt = 0; mt < 4; ++mt)
            aw[mt] = *reinterpret_cast<const short8*>(&W1l[(wb + mt * 16 + l16) * DD + kofs]);
        for (int nt = 0; nt < 4; ++nt)
            bn[nt] = *reinterpret_cast<const short8*>(&sU[(nt * 16 + l16) * 136 + kofs]);
        for (int mt = 0; mt < 4; ++mt)
            for (int nt = 0; nt < 4; ++nt)
                acc1[mt][nt] = __builtin_amdgcn_mfma_f32_16x16x32_bf16(
                    aw[mt], bn[nt], acc1[mt][nt], 0, 0, 0);
    }
    __syncthreads();   // gather view dead; z view reuses LDS

    // ---- Stage C: bias + ReLU -> sU[node][zcol] (stride 264), b64 writes ----
    for (int mt = 0; mt < 4; ++mt) {
        int zc = wb + mt * 16 + quad * 4;
        float4 bias = *reinterpret_cast<const float4*>(&b1l[zc]);
        for (int nt = 0; nt < 4; ++nt) {
            int node = nt * 16 + l16;
            short4v o;
            o.x = f2bf(fmaxf(acc1[mt][nt][0] + bias.x, 0.f));
            o.y = f2bf(fmaxf(acc1[mt][nt][1] + bias.y, 0.f));
            o.z = f2bf(fmaxf(acc1[mt][nt][2] + bias.z, 0.f));
            o.w = f2bf(fmaxf(acc1[mt][nt][3] + bias.w, 0.f));
            *reinterpret_cast<short4v*>(&sU[node * 264 + zc]) = o;
        }
    }
    __syncthreads();

    // ---- Stage D: GEMM2' hT = W2(A) x z(B); wave owns 32 outcols x 64 nodes ----
    f32x4 acc2[2][4];
    for (int ct = 0; ct < 2; ++ct)
        for (int nt = 0; nt < 4; ++nt) acc2[ct][nt] = zero4;

    const int c2 = wave * 32;
    for (int ks = 0; ks < 8; ++ks) {
        int kofs = ks * 32 + quad * 8;
        short8 aw[2], bn[4];
        for (int ct = 0; ct < 2; ++ct)
            aw[ct] = *reinterpret_cast<const short8*>(&W2l[(c2 + ct * 16 + l16) * HH + kofs]);
        for (int nt = 0; nt < 4; ++nt)
            bn[nt] = *reinterpret_cast<const short8*>(&sU[(nt * 16 + l16) * 264 + kofs]);
        for (int ct = 0; ct < 2; ++ct)
            for (int nt = 0; nt < 4; ++nt)
                acc2[ct][nt] = __builtin_amdgcn_mfma_f32_16x16x32_bf16(
                    aw[ct], bn[nt], acc2[ct][nt], 0, 0, 0);
    }

    // ---- Stage E: bias (+ReLU) -> vectorized global stores ----
    for (int ct = 0; ct < 2; ++ct) {
        int oc = c2 + ct * 16 + quad * 4;
        float4 bias = *reinterpret_cast<const float4*>(&b2l[oc]);
        for (int nt = 0; nt < 4; ++nt) {
            int node = r0 + nt * 16 + l16;
            if (node < ND) {
                float v0 = acc2[ct][nt][0] + bias.x;
                float v1 = acc2[ct][nt][1] + bias.y;
                float v2 = acc2[ct][nt][2] + bias.z;
                float v3 = acc2[ct][nt][3] + bias.w;
                if (!last) {
                    short4v o;
                    o.x = f2bf(fmaxf(v0, 0.f));
                    o.y = f2bf(fmaxf(v1, 0.f));
                    o.z = f2bf(fmaxf(v2, 0.f));
                    o.w = f2bf(fmaxf(v3, 0.f));
                    *reinterpret_cast<short4v*>(&hb_out[(size_t)node * DD + oc]) = o;
                } else {
                    float4 st; st.x = v0; st.y = v1; st.z = v2; st.w = v3;
                    *reinterpret_cast<float4*>(&f_out[(size_t)node * DD + oc]) = st;
                }
            }
        }
    }
}

extern "C" void kernel_launch(void* const* d_in, const int* in_sizes, int n_in,
                              void* d_out, int out_size, void* d_ws, size_t ws_size,
                              hipStream_t stream)
{
    const float* x  = (const float*)d_in[0];
    const int* ei   = (const int*)d_in[1];
    const int* src  = ei;
    const int* dst  = ei + EE;
    const float* W1 = (const float*)d_in[2];
    const float* b1 = (const float*)d_in[3];
    const float* g1 = (const float*)d_in[4];
    const float* bb1= (const float*)d_in[5];
    const float* m1 = (const float*)d_in[6];
    const float* v1 = (const float*)d_in[7];
    const float* W2 = (const float*)d_in[8];
    const float* b2 = (const float*)d_in[9];
    const float* g2 = (const float*)d_in[10];
    const float* bb2= (const float*)d_in[11];
    const float* m2 = (const float*)d_in[12];
    const float* v2 = (const float*)d_in[13];

    char* w = (char*)d_ws;
    short* hbufA = (short*)w;                                 // 25,600,000
    short* hbufB = (short*)(w + 25600000);                    // 25,600,000
    short* W1p   = (short*)(w + 51200000);                    //    327,680
    short* W2p   = (short*)(w + 51527680);                    //    327,680
    float* b1e   = (float*)(w + 51855360);                    //      5,120
    float* b2e   = (float*)(w + 51860480);                    //      2,560
    int*   cnt   = (int*)  (w + 51863040);                    //    400,000
    int*   cursor= (int*)  (w + 52263040);                    //    400,000 (contiguous after cnt)
    int*   rowst = (int*)  (w + 52663040);                    //    400,032
    int*   csr   = (int*)  (w + 53063072);                    //  2,560,000
    int*   bsum  = (int*)  (w + 55623072);                    //      1,664
    int*   boffs = (int*)  (w + 55624736);                    //      1,600
    float* out   = (float*)d_out;

    zero_counts<<<196, 256, 0, stream>>>(cnt);       // cnt + cursor
    setup<<<15640, 256, 0, stream>>>(W1, b1, g1, bb1, m1, v1,
                                     W2, b2, g2, bb2, m2, v2,
                                     x, dst, W1p, b1e, W2p, b2e, hbufA, cnt);
    scan_block<<<391, 256, 0, stream>>>(cnt, bsum);
    scan_bsum<<<1, 512, 0, stream>>>(bsum, boffs);
    apply_offs<<<391, 256, 0, stream>>>(cnt, boffs, rowst);
    fill_csr<<<2500, 256, 0, stream>>>(src, dst, rowst, cursor, csr);

    short* hin = hbufA;
    short* hout = hbufB;
    for (int l = 0; l < LL; ++l) {
        layer_fused<<<1563, 256, 0, stream>>>(hin, rowst, csr,
                                              W1p + l * 32768, b1e + l * HH,
                                              W2p + l * 32768, b2e + l * DD,
                                              hout, out, (l == LL - 1) ? 1 : 0);
        short* t = hin; hin = hout; hout = t;
    }
}